// Round 1
// baseline (125.890 us; speedup 1.0000x reference)
//
#include <hip/hip_runtime.h>

// Density-Aware Chamfer Loss, B=8, N=M=4096, fp32.
// loss = mean(minD_p2g / (dens_p/4095 + eps)) + mean(minD_g2p / (dens_g/4095 + eps))

#define NPTS   4096
#define NBATCH 8
#define SPLIT  8
#define JCH    (NPTS / SPLIT)          // 512 j-points per split
#define TPB    256
#define IPT    2                        // i-points per thread
#define IBLK   (TPB * IPT)              // 512 i-points per block
#define NIBLK  ((NBATCH * NPTS) / IBLK) // 64
#define TOTPTS (NBATCH * NPTS)          // 32768
#define NDIR   2
#define PARTN  (NDIR * TOTPTS)          // 65536

#define BIGF 3.4e38f

// ---- main kernel: per (dir, i-block, split): partial min-dist and partial density ----
__global__ __launch_bounds__(TPB) void dacl_main(
    const float* __restrict__ pred, const float* __restrict__ gt,
    const float* __restrict__ bwp,  const float* __restrict__ bwg,
    float* __restrict__ minPart, float* __restrict__ densPart)
{
    __shared__ float4 s4[JCH * 3 / 4];   // 6 KB staging for one chunk
    float* sP = (float*)s4;

    const int bid   = blockIdx.x;
    const int split = bid & (SPLIT - 1);        // bits 0..2
    const int ib    = (bid >> 3) & (NIBLK - 1); // bits 3..8
    const int dir   = bid >> 9;                 // bit 9

    const float* __restrict__ X = dir ? gt : pred;   // query cloud (density over X)
    const float* __restrict__ Y = dir ? pred : gt;   // target cloud (min dist to Y)
    const float bw = dir ? bwg[0] : bwp[0];
    const float nscale = -0.5f / (bw * bw);

    const int tid = threadIdx.x;
    const int p0  = ib * IBLK + tid;   // global point index [0, 32768)
    const int p1  = p0 + TPB;
    const int b   = p0 >> 12;          // batch (block fully inside one batch)

    const float x0 = X[p0*3+0], y0 = X[p0*3+1], z0 = X[p0*3+2];
    const float x1 = X[p1*3+0], y1 = X[p1*3+1], z1 = X[p1*3+2];

    const size_t coff = (size_t)(b * NPTS + split * JCH) * 3;  // chunk float offset

    // ================= pass 1: min squared distance to Y-chunk =================
    {
        const float2* src = (const float2*)(Y + coff);
        float2* dst = (float2*)sP;
        #pragma unroll
        for (int t = 0; t < (JCH*3/2)/TPB; ++t)   // 768 float2 / 256 thr = 3
            dst[tid + t*TPB] = src[tid + t*TPB];
    }
    __syncthreads();

    float m00=BIGF, m01=BIGF, m02=BIGF, m03=BIGF;
    float m10=BIGF, m11=BIGF, m12=BIGF, m13=BIGF;

    #pragma unroll 4
    for (int k = 0; k < JCH/4; ++k) {
        const float4 A  = s4[3*k+0];
        const float4 B4 = s4[3*k+1];
        const float4 C4 = s4[3*k+2];
        // q0=(A.x,A.y,A.z) q1=(A.w,B4.x,B4.y) q2=(B4.z,B4.w,C4.x) q3=(C4.y,C4.z,C4.w)
        {   float dx=x0-A.x,  dy=y0-A.y,  dz=z0-A.z;
            m00 = fminf(m00, dx*dx + dy*dy + dz*dz);
            float ex=x1-A.x,  ey=y1-A.y,  ez=z1-A.z;
            m10 = fminf(m10, ex*ex + ey*ey + ez*ez); }
        {   float dx=x0-A.w,  dy=y0-B4.x, dz=z0-B4.y;
            m01 = fminf(m01, dx*dx + dy*dy + dz*dz);
            float ex=x1-A.w,  ey=y1-B4.x, ez=z1-B4.y;
            m11 = fminf(m11, ex*ex + ey*ey + ez*ez); }
        {   float dx=x0-B4.z, dy=y0-B4.w, dz=z0-C4.x;
            m02 = fminf(m02, dx*dx + dy*dy + dz*dz);
            float ex=x1-B4.z, ey=y1-B4.w, ez=z1-C4.x;
            m12 = fminf(m12, ex*ex + ey*ey + ez*ez); }
        {   float dx=x0-C4.y, dy=y0-C4.z, dz=z0-C4.w;
            m03 = fminf(m03, dx*dx + dy*dy + dz*dz);
            float ex=x1-C4.y, ey=y1-C4.z, ez=z1-C4.w;
            m13 = fminf(m13, ex*ex + ey*ey + ez*ez); }
    }
    const float m0 = fminf(fminf(m00, m01), fminf(m02, m03));
    const float m1 = fminf(fminf(m10, m11), fminf(m12, m13));

    __syncthreads();   // done reading sP before restaging

    // ================= pass 2: KDE density vs X-chunk =================
    {
        const float2* src = (const float2*)(X + coff);
        float2* dst = (float2*)sP;
        #pragma unroll
        for (int t = 0; t < (JCH*3/2)/TPB; ++t)
            dst[tid + t*TPB] = src[tid + t*TPB];
    }
    __syncthreads();

    float d00=0.f, d01=0.f, d02=0.f, d03=0.f;
    float d10=0.f, d11=0.f, d12=0.f, d13=0.f;

    #pragma unroll 4
    for (int k = 0; k < JCH/4; ++k) {
        const float4 A  = s4[3*k+0];
        const float4 B4 = s4[3*k+1];
        const float4 C4 = s4[3*k+2];
        {   float dx=x0-A.x,  dy=y0-A.y,  dz=z0-A.z;
            d00 += __expf((dx*dx + dy*dy + dz*dz) * nscale);
            float ex=x1-A.x,  ey=y1-A.y,  ez=z1-A.z;
            d10 += __expf((ex*ex + ey*ey + ez*ez) * nscale); }
        {   float dx=x0-A.w,  dy=y0-B4.x, dz=z0-B4.y;
            d01 += __expf((dx*dx + dy*dy + dz*dz) * nscale);
            float ex=x1-A.w,  ey=y1-B4.x, ez=z1-B4.y;
            d11 += __expf((ex*ex + ey*ey + ez*ez) * nscale); }
        {   float dx=x0-B4.z, dy=y0-B4.w, dz=z0-C4.x;
            d02 += __expf((dx*dx + dy*dy + dz*dz) * nscale);
            float ex=x1-B4.z, ey=y1-B4.w, ez=z1-C4.x;
            d12 += __expf((ex*ex + ey*ey + ez*ez) * nscale); }
        {   float dx=x0-C4.y, dy=y0-C4.z, dz=z0-C4.w;
            d03 += __expf((dx*dx + dy*dy + dz*dz) * nscale);
            float ex=x1-C4.y, ey=y1-C4.z, ez=z1-C4.w;
            d13 += __expf((ex*ex + ey*ey + ez*ez) * nscale); }
    }
    const float dsum0 = (d00 + d01) + (d02 + d03);
    const float dsum1 = (d10 + d11) + (d12 + d13);

    const int o = split * PARTN + dir * TOTPTS;
    minPart[o + p0]  = m0;
    minPart[o + p1]  = m1;
    densPart[o + p0] = dsum0;
    densPart[o + p1] = dsum1;
}

// ---- combine: reduce over splits, form per-point loss term, per-block sums ----
__global__ __launch_bounds__(256) void dacl_combine(
    const float* __restrict__ minPart, const float* __restrict__ densPart,
    float* __restrict__ bsum)
{
    const int g = blockIdx.x * 256 + threadIdx.x;   // [0, 65536)
    float mn = BIGF, dn = 0.f;
    #pragma unroll
    for (int s = 0; s < SPLIT; ++s) {
        mn  = fminf(mn, minPart[(size_t)s * PARTN + g]);
        dn +=            densPart[(size_t)s * PARTN + g];
    }
    float val = mn / (dn * (1.0f/4095.0f) + 1e-6f) * (1.0f/32768.0f);

    #pragma unroll
    for (int off = 32; off; off >>= 1) val += __shfl_down(val, off);
    __shared__ float sm[4];
    const int lane = threadIdx.x & 63, wid = threadIdx.x >> 6;
    if (lane == 0) sm[wid] = val;
    __syncthreads();
    if (threadIdx.x == 0) bsum[blockIdx.x] = (sm[0] + sm[1]) + (sm[2] + sm[3]);
}

// ---- final: sum 256 block sums ----
__global__ __launch_bounds__(256) void dacl_final(
    const float* __restrict__ bsum, float* __restrict__ out)
{
    float v = bsum[threadIdx.x];
    #pragma unroll
    for (int off = 32; off; off >>= 1) v += __shfl_down(v, off);
    __shared__ float sm[4];
    const int lane = threadIdx.x & 63, wid = threadIdx.x >> 6;
    if (lane == 0) sm[wid] = v;
    __syncthreads();
    if (threadIdx.x == 0) out[0] = (sm[0] + sm[1]) + (sm[2] + sm[3]);
}

extern "C" void kernel_launch(void* const* d_in, const int* in_sizes, int n_in,
                              void* d_out, int out_size, void* d_ws, size_t ws_size,
                              hipStream_t stream)
{
    const float* pred = (const float*)d_in[0];
    const float* gt   = (const float*)d_in[1];
    const float* bwp  = (const float*)d_in[2];
    const float* bwg  = (const float*)d_in[3];

    float* ws       = (float*)d_ws;
    float* minPart  = ws;                                   // SPLIT * PARTN floats
    float* densPart = ws + (size_t)SPLIT * PARTN;           // SPLIT * PARTN floats
    float* bsum     = densPart + (size_t)SPLIT * PARTN;     // 256 floats

    dacl_main<<<NDIR * NIBLK * SPLIT, TPB, 0, stream>>>(pred, gt, bwp, bwg,
                                                        minPart, densPart);
    dacl_combine<<<PARTN / 256, 256, 0, stream>>>(minPart, densPart, bsum);
    dacl_final<<<1, 256, 0, stream>>>(bsum, (float*)d_out);
}